// Round 3
// baseline (280.961 us; speedup 1.0000x reference)
//
#include <hip/hip_runtime.h>

typedef float f32x4 __attribute__((ext_vector_type(4)));

#define V_THRESH 1.0f
#define TAU_REFRAC 0.1f

// Monotone map: float -> uint such that uint compare == float compare.
__device__ __forceinline__ unsigned int map_f32(float f) {
    unsigned int u = __float_as_uint(f);
    return (u & 0x80000000u) ? ~u : (u | 0x80000000u);
}
__device__ __forceinline__ float unmap_f32(unsigned int m) {
    unsigned int u = (m & 0x80000000u) ? (m & 0x7fffffffu) : ~m;
    return __uint_as_float(u);
}

// d_ws layout: ws[0] = running max (mapped), ws[1] = done-block ticket counter.
__global__ void init_ws_kernel(unsigned int* ws) {
    ws[0] = 0u;   // below any mapped real value -> identity for max
    ws[1] = 0u;
}

// Process 4 lanes held in float arrays (compile-time indexed -> registers).
__device__ __forceinline__ void neuron4(const f32x4 im, const f32x4 me,
                                        const f32x4 rf, const f32x4 pl,
                                        const f32x4 ps, const f32x4 sc,
                                        float t, float t_end,
                                        f32x4& vsp, f32x4& vmem, f32x4& vrf,
                                        f32x4& vpl, f32x4& vps, f32x4& vsc,
                                        f32x4& vst, float& lmax) {
    #pragma unroll
    for (int j = 0; j < 4; ++j) {
        float imp = im[j], m0 = me[j], r0 = rf[j];
        float p0 = pl[j], s0 = ps[j], c0 = sc[j];
        float mi = (r0 > t) ? 0.0f : imp;      // masked impulse
        float nm = m0 + mi;                    // new_mem
        bool spiked = (nm >= V_THRESH);
        float sp = spiked ? 1.0f : 0.0f;
        float resid = nm - V_THRESH;
        float new_pl = resid - s0;             // two-step, matches reference rounding
        vsp[j]  = sp * V_THRESH;
        vmem[j] = nm - V_THRESH * sp;          // reset by subtraction
        vpl[j]  = spiked ? new_pl : p0;
        vps[j]  = spiked ? (s0 + new_pl) : s0;
        vrf[j]  = spiked ? t_end : r0;
        float c1 = c0 + sp;
        vsc[j]  = c1;
        vst[j]  = t * sp;
        lmax = fmaxf(lmax, c1);
    }
}

__global__ __launch_bounds__(256) void spike_kernel(
    const f32x4* __restrict__ impulse,
    const f32x4* __restrict__ mem,
    const f32x4* __restrict__ refrac,
    const f32x4* __restrict__ payloads,
    const f32x4* __restrict__ paysum,
    const f32x4* __restrict__ spikecounts,
    const float* __restrict__ time,
    f32x4* __restrict__ out,           // 7 contiguous planes, n4 float4 each
    float* __restrict__ out_scalar,    // out + 7*N scalar slot
    unsigned int* __restrict__ ws,
    int n4)
{
    const float t = time[0];
    const float t_end = t + TAU_REFRAC;

    f32x4* __restrict__ o_sp  = out;
    f32x4* __restrict__ o_mem = out + (size_t)n4;
    f32x4* __restrict__ o_rf  = out + 2 * (size_t)n4;
    f32x4* __restrict__ o_pl  = out + 3 * (size_t)n4;
    f32x4* __restrict__ o_ps  = out + 4 * (size_t)n4;
    f32x4* __restrict__ o_sc  = out + 5 * (size_t)n4;
    f32x4* __restrict__ o_st  = out + 6 * (size_t)n4;

    float lmax = -__builtin_inff();
    const long stride = (long)gridDim.x * blockDim.x;
    long i = (long)blockIdx.x * blockDim.x + threadIdx.x;
    const long niter = (long)n4 / stride;   // exact: 4194304 / 524288 = 8

    #pragma unroll 1
    for (long k = 0; k < niter; ++k, i += stride) {
        f32x4 im = __builtin_nontemporal_load(&impulse[i]);
        f32x4 me = __builtin_nontemporal_load(&mem[i]);
        f32x4 rf = __builtin_nontemporal_load(&refrac[i]);
        f32x4 pl = __builtin_nontemporal_load(&payloads[i]);
        f32x4 ps = __builtin_nontemporal_load(&paysum[i]);
        f32x4 sc = __builtin_nontemporal_load(&spikecounts[i]);
        f32x4 vsp, vmem, vrf, vpl, vps, vsc, vst;

        neuron4(im, me, rf, pl, ps, sc, t, t_end,
                vsp, vmem, vrf, vpl, vps, vsc, vst, lmax);

        __builtin_nontemporal_store(vsp,  &o_sp[i]);
        __builtin_nontemporal_store(vmem, &o_mem[i]);
        __builtin_nontemporal_store(vrf,  &o_rf[i]);
        __builtin_nontemporal_store(vpl,  &o_pl[i]);
        __builtin_nontemporal_store(vps,  &o_ps[i]);
        __builtin_nontemporal_store(vsc,  &o_sc[i]);
        __builtin_nontemporal_store(vst,  &o_st[i]);
    }
    // tail (empty for the bench shape, kept for generality)
    if (i < (long)n4) {
        f32x4 im = impulse[i], me = mem[i], rf = refrac[i];
        f32x4 pl = payloads[i], ps = paysum[i], sc = spikecounts[i];
        f32x4 vsp, vmem, vrf, vpl, vps, vsc, vst;
        neuron4(im, me, rf, pl, ps, sc, t, t_end,
                vsp, vmem, vrf, vpl, vps, vsc, vst, lmax);
        o_sp[i] = vsp; o_mem[i] = vmem; o_rf[i] = vrf; o_pl[i] = vpl;
        o_ps[i] = vps; o_sc[i] = vsc; o_st[i] = vst;
    }

    // 64-lane butterfly max reduce, one atomic per wave
    #pragma unroll
    for (int off = 32; off > 0; off >>= 1)
        lmax = fmaxf(lmax, __shfl_xor(lmax, off));
    if ((threadIdx.x & 63) == 0)
        atomicMax(&ws[0], map_f32(lmax));

    // fused finalize: last block to finish computes the scalar
    __syncthreads();
    if (threadIdx.x == 0) {
        __threadfence();                              // release our atomicMax
        unsigned int ticket = atomicAdd(&ws[1], 1u);
        if (ticket == gridDim.x - 1) {
            __threadfence();                          // acquire all atomicMax
            unsigned int m = atomicMax(&ws[0], 0u);   // atomic read (0 never raises)
            out_scalar[0] = unmap_f32(m) * (1.0f / t);
        }
    }
}

extern "C" void kernel_launch(void* const* d_in, const int* in_sizes, int n_in,
                              void* d_out, int out_size, void* d_ws, size_t ws_size,
                              hipStream_t stream) {
    const f32x4* impulse     = (const f32x4*)d_in[0];
    const f32x4* mem         = (const f32x4*)d_in[1];
    const f32x4* refrac      = (const f32x4*)d_in[2];
    const f32x4* payloads    = (const f32x4*)d_in[3];
    const f32x4* paysum      = (const f32x4*)d_in[4];
    const f32x4* spikecounts = (const f32x4*)d_in[5];
    const float* time        = (const float*)d_in[6];

    const int n  = in_sizes[0];      // 16777216
    const int n4 = n / 4;
    float* out = (float*)d_out;
    unsigned int* ws = (unsigned int*)d_ws;

    init_ws_kernel<<<1, 1, 0, stream>>>(ws);
    spike_kernel<<<2048, 256, 0, stream>>>(impulse, mem, refrac, payloads,
                                           paysum, spikecounts, time,
                                           (f32x4*)out, out + 7 * (size_t)n,
                                           ws, n4);
}